// Round 1
// baseline (163.692 us; speedup 1.0000x reference)
//
#include <hip/hip_runtime.h>
#include <hip/hip_bf16.h>

#define TWO_N 8192
#define NHALF 4096
#define D 256
static constexpr float INV_T = 2.0f; // 1 / 0.5

typedef __attribute__((ext_vector_type(8))) short short8;
typedef __attribute__((ext_vector_type(4))) float f32x4;

__device__ __forceinline__ float bfu2f(ushort u) {
    unsigned int x = ((unsigned int)u) << 16;
    return __uint_as_float(x);
}

// ---------------- kernel 1: row-normalize to bf16, zero denom ----------------
__global__ __launch_bounds__(256) void normalize_kernel(
        const float* __restrict__ z_i, const float* __restrict__ z_j,
        ushort* __restrict__ zn, float* __restrict__ denom) {
    const int row = blockIdx.x;
    const int tid = threadIdx.x;
    const float* src = (row < NHALF) ? (z_i + (size_t)row * D)
                                     : (z_j + (size_t)(row - NHALF) * D);
    float v = src[tid];
    float ss = v * v;
    #pragma unroll
    for (int off = 32; off; off >>= 1) ss += __shfl_down(ss, off);
    __shared__ float red[4];
    const int wid = tid >> 6, lane = tid & 63;
    if (lane == 0) red[wid] = ss;
    __syncthreads();
    const float total = red[0] + red[1] + red[2] + red[3];
    const float rn = rsqrtf(total);
    const float nv = v * rn;
    __hip_bfloat16 b = __float2bfloat16(nv);
    zn[(size_t)row * D + tid] = *reinterpret_cast<const ushort*>(&b);
    if (tid == 0) denom[row] = 0.0f;
}

// ---------------- kernel 2: positive-pair similarity ----------------
// one wave per row: sim_pos[i] = (1/T) * dot(zn[i], zn[(i+N) mod 2N])
__global__ __launch_bounds__(256) void pos_kernel(
        const ushort* __restrict__ zn, float* __restrict__ sim_pos) {
    const int wid = threadIdx.x >> 6;
    const int lane = threadIdx.x & 63;
    const int i = blockIdx.x * 4 + wid;
    const int p = (i + NHALF) & (TWO_N - 1);
    const ushort* a = zn + (size_t)i * D;
    const ushort* b = zn + (size_t)p * D;
    float s = 0.f;
    #pragma unroll
    for (int jj = 0; jj < 4; ++jj) {
        const int j = lane * 4 + jj;
        s += bfu2f(a[j]) * bfu2f(b[j]);
    }
    #pragma unroll
    for (int off = 32; off; off >>= 1) s += __shfl_down(s, off);
    if (lane == 0) sim_pos[i] = s * INV_T;
}

// ---------------- kernel 3: fused sim-GEMM + exp + row-sum ----------------
// 128x128 tile per block, 4 waves, each wave: 32 rows x 128 cols.
// mfma_f32_16x16x32_bf16; A row = lane&15, k = 8*(lane>>4)+j (contiguous 16B);
// B col = lane&15, same k runs -> also contiguous rows of zn (B = zn^T).
// C/D: col = lane&15, row = 4*(lane>>4) + reg.
__global__ __launch_bounds__(256) void gemm_denom_kernel(
        const ushort* __restrict__ zn, float* __restrict__ denom) {
    const int lane = threadIdx.x & 63;
    const int wid  = threadIdx.x >> 6;
    const int tr = blockIdx.x;
    const int tc = blockIdx.y;
    const int row0 = tr * 128 + wid * 32;
    const int col0 = tc * 128;
    const int r16  = lane & 15;
    const int kgrp = lane >> 4;

    f32x4 acc[2][8];
    #pragma unroll
    for (int m = 0; m < 2; ++m)
        #pragma unroll
        for (int n = 0; n < 8; ++n) {
            f32x4 z = {0.f, 0.f, 0.f, 0.f};
            acc[m][n] = z;
        }

    for (int k0 = 0; k0 < D; k0 += 32) {
        const int k = k0 + kgrp * 8;
        short8 a[2], b[8];
        #pragma unroll
        for (int m = 0; m < 2; ++m) {
            const int r = row0 + m * 16 + r16;
            a[m] = *reinterpret_cast<const short8*>(zn + (size_t)r * D + k);
        }
        #pragma unroll
        for (int n = 0; n < 8; ++n) {
            const int c = col0 + n * 16 + r16;
            b[n] = *reinterpret_cast<const short8*>(zn + (size_t)c * D + k);
        }
        #pragma unroll
        for (int m = 0; m < 2; ++m)
            #pragma unroll
            for (int n = 0; n < 8; ++n)
                acc[m][n] = __builtin_amdgcn_mfma_f32_16x16x32_bf16(
                    a[m], b[n], acc[m][n], 0, 0, 0);
    }

    // epilogue: scale, exp, zero diagonal, row-sum across the 128 cols
    #pragma unroll
    for (int m = 0; m < 2; ++m) {
        #pragma unroll
        for (int reg = 0; reg < 4; ++reg) {
            const int r = row0 + m * 16 + kgrp * 4 + reg;
            float rs = 0.f;
            #pragma unroll
            for (int n = 0; n < 8; ++n) {
                const int c = col0 + n * 16 + r16;
                const float e = __expf(acc[m][n][reg] * INV_T);
                rs += (r == c) ? 0.f : e;
            }
            rs += __shfl_xor(rs, 1);
            rs += __shfl_xor(rs, 2);
            rs += __shfl_xor(rs, 4);
            rs += __shfl_xor(rs, 8);
            if (r16 == 0) atomicAdd(&denom[r], rs);
        }
    }
}

// ---------------- kernel 4: final loss reduction ----------------
__global__ __launch_bounds__(1024) void final_kernel(
        const float* __restrict__ sim_pos, const float* __restrict__ denom,
        float* __restrict__ out) {
    const int tid = threadIdx.x;
    float s = 0.f;
    for (int i = tid; i < TWO_N; i += 1024)
        s += sim_pos[i] - logf(denom[i]);
    #pragma unroll
    for (int off = 32; off; off >>= 1) s += __shfl_down(s, off);
    __shared__ float red[16];
    const int wid = tid >> 6, lane = tid & 63;
    if (lane == 0) red[wid] = s;
    __syncthreads();
    if (tid == 0) {
        float t = 0.f;
        #pragma unroll
        for (int w = 0; w < 16; ++w) t += red[w];
        out[0] = -t / (float)TWO_N;
    }
}

extern "C" void kernel_launch(void* const* d_in, const int* in_sizes, int n_in,
                              void* d_out, int out_size, void* d_ws, size_t ws_size,
                              hipStream_t stream) {
    const float* z_i = (const float*)d_in[0];
    const float* z_j = (const float*)d_in[1];
    float* out = (float*)d_out;

    ushort* zn      = (ushort*)d_ws;                                  // 4 MB
    float*  sim_pos = (float*)((char*)d_ws + (size_t)TWO_N * D * 2);  // 32 KB
    float*  denom   = sim_pos + TWO_N;                                // 32 KB

    normalize_kernel<<<TWO_N, 256, 0, stream>>>(z_i, z_j, zn, denom);
    pos_kernel<<<TWO_N / 4, 256, 0, stream>>>(zn, sim_pos);
    dim3 grid(TWO_N / 128, TWO_N / 128);
    gemm_denom_kernel<<<grid, 256, 0, stream>>>(zn, denom);
    final_kernel<<<1, 1024, 0, stream>>>(sim_pos, denom, out);
}

// Round 2
// 62.494 us; speedup vs baseline: 2.6193x; 2.6193x over previous
//
#include <hip/hip_runtime.h>
#include <hip/hip_bf16.h>

#define TWO_N 8192
#define NHALF 4096
#define D 256
static constexpr float INV_T = 2.0f; // 1 / 0.5

typedef __attribute__((ext_vector_type(8))) short short8;
typedef __attribute__((ext_vector_type(4))) float f32x4;

#define AS1 __attribute__((address_space(1)))
#define AS3 __attribute__((address_space(3)))

__device__ __forceinline__ float bfu2f(ushort u) {
    unsigned int x = ((unsigned int)u) << 16;
    return __uint_as_float(x);
}

// ---------------- kernel 1: row-normalize to bf16, zero denom ----------------
__global__ __launch_bounds__(256) void normalize_kernel(
        const float* __restrict__ z_i, const float* __restrict__ z_j,
        ushort* __restrict__ zn, float* __restrict__ denom) {
    const int row = blockIdx.x;
    const int tid = threadIdx.x;
    const float* src = (row < NHALF) ? (z_i + (size_t)row * D)
                                     : (z_j + (size_t)(row - NHALF) * D);
    float v = src[tid];
    float ss = v * v;
    #pragma unroll
    for (int off = 32; off; off >>= 1) ss += __shfl_down(ss, off);
    __shared__ float red[4];
    const int wid = tid >> 6, lane = tid & 63;
    if (lane == 0) red[wid] = ss;
    __syncthreads();
    const float total = red[0] + red[1] + red[2] + red[3];
    const float rn = rsqrtf(total);
    const float nv = v * rn;
    __hip_bfloat16 b = __float2bfloat16(nv);
    zn[(size_t)row * D + tid] = *reinterpret_cast<const ushort*>(&b);
    if (tid == 0) denom[row] = 0.0f;
}

// ---------------- kernel 2: positive-pair similarity ----------------
__global__ __launch_bounds__(256) void pos_kernel(
        const ushort* __restrict__ zn, float* __restrict__ sim_pos) {
    const int wid = threadIdx.x >> 6;
    const int lane = threadIdx.x & 63;
    const int i = blockIdx.x * 4 + wid;
    const int p = (i + NHALF) & (TWO_N - 1);
    const ushort* a = zn + (size_t)i * D;
    const ushort* b = zn + (size_t)p * D;
    float s = 0.f;
    #pragma unroll
    for (int jj = 0; jj < 4; ++jj) {
        const int j = lane * 4 + jj;
        s += bfu2f(a[j]) * bfu2f(b[j]);
    }
    #pragma unroll
    for (int off = 32; off; off >>= 1) s += __shfl_down(s, off);
    if (lane == 0) sim_pos[i] = s * INV_T;
}

// ---------------- kernel 3: fused symmetric sim-GEMM + exp + row/col sums ----
// m97 structure: BM=BN=128, BK=32, 4 waves (2x2), per-wave 64x64 output.
// global_load_lds width-16 staging, 8 ds_read_b128 + 16 MFMA per K-step.
// Symmetry: only tiles tc >= tr are computed. Off-diagonal tiles contribute
// row-sums to denom[r] and col-sums to denom[c] (mirror tile's row-sums).
// Diagonal tiles: row-sums only, with exact r==c zeroing.
__global__ __launch_bounds__(256) void gemm_denom_kernel(
        const ushort* __restrict__ zn, float* __restrict__ denom) {
    const int tr = blockIdx.x;
    const int tc = blockIdx.y;
    if (tc < tr) return;  // upper triangle only (block-uniform exit, pre-sync)

    __shared__ ushort As[128 * 32];  // 8 KB, row-major [128][32]
    __shared__ ushort Bs[128 * 32];  // 8 KB

    const int tid  = threadIdx.x;
    const int lane = tid & 63;
    const int wid  = tid >> 6;
    const int wr   = wid >> 1;       // wave row (0..1)
    const int wc   = wid & 1;        // wave col (0..1)
    const int r16  = lane & 15;
    const int kgrp = lane >> 4;

    const int row0 = tr * 128;
    const int col0 = tc * 128;

    f32x4 acc[4][4];
    #pragma unroll
    for (int m = 0; m < 4; ++m)
        #pragma unroll
        for (int n = 0; n < 4; ++n) {
            f32x4 z = {0.f, 0.f, 0.f, 0.f};
            acc[m][n] = z;
        }

    for (int k0 = 0; k0 < D; k0 += 32) {
        // ---- stage: 512 16B chunks per tile, 2 per thread per tile ----
        #pragma unroll
        for (int i = 0; i < 2; ++i) {
            const int c = (i * 4 + wid) * 64 + lane;     // chunk id 0..511
            const int r = c >> 2;                        // tile row
            const int kc = (c & 3) * 8;                  // col elem within BK
            const ushort* ga = zn + (size_t)(row0 + r) * D + k0 + kc;
            const ushort* gb = zn + (size_t)(col0 + r) * D + k0 + kc;
            __builtin_amdgcn_global_load_lds(
                (const AS1 void*)ga, (AS3 void*)(As + (i * 4 + wid) * 512), 16, 0, 0);
            __builtin_amdgcn_global_load_lds(
                (const AS1 void*)gb, (AS3 void*)(Bs + (i * 4 + wid) * 512), 16, 0, 0);
        }
        __syncthreads();

        // ---- compute: 8 ds_read_b128 + 16 MFMA ----
        short8 a[4], b[4];
        #pragma unroll
        for (int m = 0; m < 4; ++m)
            a[m] = *reinterpret_cast<const short8*>(
                As + (wr * 64 + m * 16 + r16) * 32 + kgrp * 8);
        #pragma unroll
        for (int n = 0; n < 4; ++n)
            b[n] = *reinterpret_cast<const short8*>(
                Bs + (wc * 64 + n * 16 + r16) * 32 + kgrp * 8);
        #pragma unroll
        for (int m = 0; m < 4; ++m)
            #pragma unroll
            for (int n = 0; n < 4; ++n)
                acc[m][n] = __builtin_amdgcn_mfma_f32_16x16x32_bf16(
                    a[m], b[n], acc[m][n], 0, 0, 0);
        __syncthreads();
    }

    // ---- epilogue: exp, diag zero, row sums (+ col sums if off-diagonal) ----
    const bool offdiag = (tr != tc);
    float cs[4] = {0.f, 0.f, 0.f, 0.f};
    #pragma unroll
    for (int m = 0; m < 4; ++m) {
        #pragma unroll
        for (int reg = 0; reg < 4; ++reg) {
            const int rg = row0 + wr * 64 + m * 16 + kgrp * 4 + reg;
            float rs = 0.f;
            #pragma unroll
            for (int n = 0; n < 4; ++n) {
                const int cg = col0 + wc * 64 + n * 16 + r16;
                float e = __expf(acc[m][n][reg] * INV_T);
                if (rg == cg) e = 0.f;   // only possible when tr==tc
                rs += e;
                cs[n] += e;
            }
            rs += __shfl_xor(rs, 1);
            rs += __shfl_xor(rs, 2);
            rs += __shfl_xor(rs, 4);
            rs += __shfl_xor(rs, 8);
            if (r16 == 0) atomicAdd(&denom[rg], rs);
        }
    }
    if (offdiag) {
        #pragma unroll
        for (int n = 0; n < 4; ++n) {
            cs[n] += __shfl_xor(cs[n], 16);
            cs[n] += __shfl_xor(cs[n], 32);
        }
        if (kgrp == 0) {
            #pragma unroll
            for (int n = 0; n < 4; ++n)
                atomicAdd(&denom[col0 + wc * 64 + n * 16 + r16], cs[n]);
        }
    }
}

// ---------------- kernel 4: final loss reduction ----------------
__global__ __launch_bounds__(1024) void final_kernel(
        const float* __restrict__ sim_pos, const float* __restrict__ denom,
        float* __restrict__ out) {
    const int tid = threadIdx.x;
    float s = 0.f;
    for (int i = tid; i < TWO_N; i += 1024)
        s += sim_pos[i] - logf(denom[i]);
    #pragma unroll
    for (int off = 32; off; off >>= 1) s += __shfl_down(s, off);
    __shared__ float red[16];
    const int wid = tid >> 6, lane = tid & 63;
    if (lane == 0) red[wid] = s;
    __syncthreads();
    if (tid == 0) {
        float t = 0.f;
        #pragma unroll
        for (int w = 0; w < 16; ++w) t += red[w];
        out[0] = -t / (float)TWO_N;
    }
}

extern "C" void kernel_launch(void* const* d_in, const int* in_sizes, int n_in,
                              void* d_out, int out_size, void* d_ws, size_t ws_size,
                              hipStream_t stream) {
    const float* z_i = (const float*)d_in[0];
    const float* z_j = (const float*)d_in[1];
    float* out = (float*)d_out;

    ushort* zn      = (ushort*)d_ws;                                  // 4 MB
    float*  sim_pos = (float*)((char*)d_ws + (size_t)TWO_N * D * 2);  // 32 KB
    float*  denom   = sim_pos + TWO_N;                                // 32 KB

    normalize_kernel<<<TWO_N, 256, 0, stream>>>(z_i, z_j, zn, denom);
    pos_kernel<<<TWO_N / 4, 256, 0, stream>>>(zn, sim_pos);
    dim3 grid(TWO_N / 128, TWO_N / 128);
    gemm_denom_kernel<<<grid, 256, 0, stream>>>(zn, denom);
    final_kernel<<<1, 1024, 0, stream>>>(sim_pos, denom, out);
}